// Round 9
// baseline (388.517 us; speedup 1.0000x reference)
//
#include <hip/hip_runtime.h>
#include <math.h>

#define B_TOT 16384
#define DD    256
#define UU    32
#define NBR   8
#define MH    512
#define RH    256
#define KIN   288
#define NY    20

typedef unsigned short u16;
typedef __attribute__((ext_vector_type(8))) short bfx8;
typedef __attribute__((ext_vector_type(4))) short bfx4;
typedef __attribute__((ext_vector_type(4))) float fx4;

#define MFMA(a, b, c) __builtin_amdgcn_mfma_f32_16x16x32_bf16((a), (b), (c), 0, 0, 0)

__device__ __forceinline__ u16 f2bf(float f) {
  __bf16 h = (__bf16)f;
  return __builtin_bit_cast(u16, h);
}
__device__ __forceinline__ float fsigmoid(float x) {
  return __builtin_amdgcn_rcpf(1.f + __expf(-x));
}
// tanh-form GELU (max |err| vs exact ~3e-4 << bf16 pack noise)
__device__ __forceinline__ float fgelu(float v) {
  float t = v * v;
  float z = v * __builtin_fmaf(t, 0.07135481627f, 1.5957691216f);
  float p = __expf(z);
  return v - v * __builtin_amdgcn_rcpf(p + 1.f);
}
// async global->LDS, 16B/lane; LDS dest wave-uniform base + lane*16
__device__ __forceinline__ void gload16(const void* g, void* l) {
  __builtin_amdgcn_global_load_lds((const __attribute__((address_space(1))) unsigned int*)(g),
                                   (__attribute__((address_space(3))) unsigned int*)(l),
                                   16, 0, 0);
}

// ---------------------------------------------------------------------------
// prep: all weights -> bf16 in MFMA fragment-packed layout:
//   pk[((m_tile*NKT + k_tile)*64 + lane)*8], lane = (m&15) + 16*((k>>3)&3)
// W1 gets sigmoid(gates) folded in; Wout transposed to [d][n*RH+r] then
// packed; ztb plain bf16.   [unchanged from R7]
// ---------------------------------------------------------------------------
__global__ __launch_bounds__(256)
void skolr_prep(const float* __restrict__ W1, const float* __restrict__ W2,
                const float* __restrict__ rnnB, const float* __restrict__ Wout,
                const float* __restrict__ gates, const float* __restrict__ zt,
                u16* __restrict__ w1g, u16* __restrict__ w2b, u16* __restrict__ bb,
                u16* __restrict__ wotb, u16* __restrict__ ztb)
{
  long i = (long)(blockIdx.x * 256 + threadIdx.x) * 8;
  const long E0 = 1048576;   // W1
  const long E1 = 2097152;   // +W2
  const long E2 = 2686976;   // +rnnB
  const long E3 = 3211264;   // +Wout
  const long E4 = 7405568;   // +zt
  if (i >= E4) return;
  if (i < E0) {
    int n = (int)(i >> 17), h = (int)((i >> 8) & 511), d = (int)(i & 255);
    const float* gp = gates + n * DD + d;
    float4 g0 = *(const float4*)gp, g1 = *(const float4*)(gp + 4);
    float4 a = *(const float4*)(W1 + i), b = *(const float4*)(W1 + i + 4);
    bfx8 v;
    v[0] = f2bf(a.x * fsigmoid(g0.x)); v[1] = f2bf(a.y * fsigmoid(g0.y));
    v[2] = f2bf(a.z * fsigmoid(g0.z)); v[3] = f2bf(a.w * fsigmoid(g0.w));
    v[4] = f2bf(b.x * fsigmoid(g1.x)); v[5] = f2bf(b.y * fsigmoid(g1.y));
    v[6] = f2bf(b.z * fsigmoid(g1.z)); v[7] = f2bf(b.w * fsigmoid(g1.w));
    u16* dst = w1g + (size_t)n * 131072
             + ((((h >> 4) << 3) + (d >> 5)) << 9) + ((h & 15) << 3) + (((d >> 3) & 3) << 7);
    *(bfx8*)dst = v;
    return;
  }
  const float* src; u16* dst; long off;
  if (i < E1) {            // W2: [n][r][k], NKT=16
    off = i - E0;
    int n = (int)(off >> 17), r = (int)((off >> 9) & 255), k = (int)(off & 511);
    src = W2 + off;
    dst = w2b + (size_t)n * 131072
        + ((((r >> 4) << 4) + (k >> 5)) << 9) + ((r & 15) << 3) + (((k >> 3) & 3) << 7);
  } else if (i < E2) {     // rnnB: [n][r][k], K=288, NKT=9
    off = i - E1;
    int o = (int)off;
    int n = o / 73728, rem = o - n * 73728;
    int r = rem / KIN, k = rem - r * KIN;
    src = rnnB + off;
    dst = bb + (size_t)n * 73728
        + (((r >> 4) * 9 + (k >> 5)) << 9) + ((r & 15) << 3) + (((k >> 3) & 3) << 7);
  } else if (i < E3) {     // Wout[n][d][r] -> A[d][k=n*256+r], NKT=64
    off = i - E2;
    int n = (int)(off >> 16), rem = (int)(off & 65535);
    int d = rem >> 8, r = rem & 255;
    src = Wout + off;
    dst = wotb + ((((d >> 4) << 6) + (n << 3) + (r >> 5)) << 9)
        + ((d & 15) << 3) + (((r >> 3) & 3) << 7);
  } else {                 // zt plain bf16
    off = i - E3;
    src = zt + off;
    dst = ztb + off;
  }
  float4 a = *(const float4*)src, b = *(const float4*)(src + 4);
  bfx8 v;
  v[0] = f2bf(a.x); v[1] = f2bf(a.y); v[2] = f2bf(a.z); v[3] = f2bf(a.w);
  v[4] = f2bf(b.x); v[5] = f2bf(b.y); v[6] = f2bf(b.z); v[7] = f2bf(b.w);
  *(bfx8*)dst = v;
}

// ---------------------------------------------------------------------------
// fused v3: 256-thread blocks (4 waves), 32-row batch tile, LDS 33KB
// -> 4 INDEPENDENT blocks/CU (same 16 waves/CU as before, but uncorrelated
// phases: one block's MFMA overlaps another's VALU pack -- m114 mechanism).
// Buffers: P=smX[0:16K], Q=smX[16K:32K] ping-pong.
// bing written in PHYSICAL (swizzled) chunk order for final's linear stage.
// ---------------------------------------------------------------------------
__global__ __launch_bounds__(256, 4)
void skolr_fused(const u16* __restrict__ ztb, const float* __restrict__ dtp,
                 const float* __restrict__ ut,
                 const u16* __restrict__ w1g, const float* __restrict__ b1,
                 const float* __restrict__ lng, const float* __restrict__ lnb,
                 const u16* __restrict__ w2g, const float* __restrict__ b2v,
                 const u16* __restrict__ rnnb, u16* __restrict__ bing)
{
  __shared__ __align__(16) char smX[32768];     // P | Q
  __shared__ __align__(16) float smR[256];      // LN partials [2][4][32]
  const int tid = threadIdx.x;
  const int w  = tid >> 6;       // 0..3
  const int l  = tid & 63;
  const int lr = l & 15;
  const int lg = l >> 4;
  const int n  = blockIdx.x;     // branch -> XCD (linear%8)
  const int b0 = blockIdx.y * 32;
  char* P = smX;
  char* Q = smX + 16384;

  // ---- S0: stage zg tile (32 rows x 512B) -> P, swizzled via source addr
  #pragma unroll
  for (int j = 0; j < 4; ++j) {
    int q = (j << 2) + w;              // 0..15, each covers rows 2q,2q+1
    int r = (q << 1) + (l >> 5);
    const u16* src = ztb + (size_t)(b0 + r) * DD + (((l & 31) ^ (r & 7)) << 3);
    gload16(src, P + (q << 10));
  }
  __syncthreads();   // S0

  // ---- GEMM1: xT[h][b] = W1'[n] @ zg^T  (M=512, N=32, K=256)
  // wave w owns h rows [w*64, w*64+64) (mt 0..3) and [256+w*64, ...) (mt 4..7)
  fx4 acc1[8][2];
  #pragma unroll
  for (int mt = 0; mt < 8; ++mt)
    #pragma unroll
    for (int nt = 0; nt < 2; ++nt)
      acc1[mt][nt] = (fx4){0.f, 0.f, 0.f, 0.f};
  {
    const u16* w1pk = w1g + (size_t)n * 131072;
    #pragma unroll
    for (int kk = 0; kk < 8; ++kk) {
      bfx8 bfr[2];
      #pragma unroll
      for (int nt = 0; nt < 2; ++nt) {
        int b = nt * 16 + lr;
        bfr[nt] = *(const bfx8*)(P + b * 512 + ((((kk << 2) + lg) ^ (b & 7)) << 4));
      }
      #pragma unroll
      for (int mt = 0; mt < 8; ++mt) {
        int mtile = (mt < 4 ? (w << 2) + mt : 16 + (w << 2) + (mt - 4));
        bfx8 af = *(const bfx8*)(w1pk + (((mtile << 3) + kk) << 9) + (l << 3));
        #pragma unroll
        for (int nt = 0; nt < 2; ++nt)
          acc1[mt][nt] = MFMA(af, bfr[nt], acc1[mt][nt]);
      }
    }
  }
  #pragma unroll
  for (int mt = 0; mt < 8; ++mt) {
    int hb = (mt < 4 ? (w << 6) + mt * 16 : 256 + (w << 6) + (mt - 4) * 16) + (lg << 2);
    fx4 bv = *(const fx4*)(b1 + n * MH + hb);
    #pragma unroll
    for (int nt = 0; nt < 2; ++nt)
      acc1[mt][nt] += bv;
  }

  // ---- LN partials (each wave covers 128 of the 512 h rows)
  #pragma unroll
  for (int nt = 0; nt < 2; ++nt) {
    float s1 = 0.f, s2 = 0.f;
    #pragma unroll
    for (int mt = 0; mt < 8; ++mt)
      #pragma unroll
      for (int r = 0; r < 4; ++r) { float v = acc1[mt][nt][r]; s1 += v; s2 += v * v; }
    s1 += __shfl_xor(s1, 16); s1 += __shfl_xor(s1, 32);
    s2 += __shfl_xor(s2, 16); s2 += __shfl_xor(s2, 32);
    if (l < 16) { smR[(w << 5) + nt * 16 + l] = s1; smR[128 + (w << 5) + nt * 16 + l] = s2; }
  }
  __syncthreads();   // B1 (also: GEMM1 reads of P done)

  // ---- stats (redundant per-thread) + LN + GELU in regs
  float meanv[2], rstdv[2];
  #pragma unroll
  for (int nt = 0; nt < 2; ++nt) {
    float ms = 0.f, ss = 0.f;
    #pragma unroll
    for (int wv = 0; wv < 4; ++wv) {
      ms += smR[(wv << 5) + nt * 16 + lr];
      ss += smR[128 + (wv << 5) + nt * 16 + lr];
    }
    float mean = ms * (1.f / 512.f);
    meanv[nt] = mean;
    rstdv[nt] = rsqrtf(ss * (1.f / 512.f) - mean * mean + 1e-5f);
  }
  #pragma unroll
  for (int mt = 0; mt < 8; ++mt) {
    int hb = (mt < 4 ? (w << 6) + mt * 16 : 256 + (w << 6) + (mt - 4) * 16) + (lg << 2);
    fx4 g4 = *(const fx4*)(lng + n * MH + hb);
    fx4 e4 = *(const fx4*)(lnb + n * MH + hb);
    #pragma unroll
    for (int nt = 0; nt < 2; ++nt)
      #pragma unroll
      for (int r = 0; r < 4; ++r) {
        float v = (acc1[mt][nt][r] - meanv[nt]) * rstdv[nt] * g4[r] + e4[r];
        acc1[mt][nt][r] = fgelu(v);
      }
  }

  // ---- pack x half0 (mt 0..3, h 0..255) -> Q [b][512B], XOR ^(b&7)
  #pragma unroll
  for (int mt = 0; mt < 4; ++mt)
    #pragma unroll
    for (int nt = 0; nt < 2; ++nt) {
      int b = nt * 16 + lr;
      bfx4 p;
      p[0] = f2bf(acc1[mt][nt][0]); p[1] = f2bf(acc1[mt][nt][1]);
      p[2] = f2bf(acc1[mt][nt][2]); p[3] = f2bf(acc1[mt][nt][3]);
      int ch = (w << 3) + (mt << 1) + (lg >> 1);
      *(bfx4*)(Q + b * 512 + ((ch ^ (b & 7)) << 4) + ((lg & 1) << 3)) = p;
    }
  __syncthreads();   // B2

  // ---- GEMM2a: gT[r][b], K = h 0..255 from Q
  fx4 acc2[4][2];
  #pragma unroll
  for (int mt = 0; mt < 4; ++mt)
    #pragma unroll
    for (int nt = 0; nt < 2; ++nt)
      acc2[mt][nt] = (fx4){0.f, 0.f, 0.f, 0.f};
  const u16* w2pk = w2g + (size_t)n * 131072;
  #pragma unroll
  for (int kk = 0; kk < 8; ++kk) {
    bfx8 xb[2];
    #pragma unroll
    for (int nt = 0; nt < 2; ++nt) {
      int b = nt * 16 + lr;
      xb[nt] = *(const bfx8*)(Q + b * 512 + ((((kk << 2) + lg) ^ (b & 7)) << 4));
    }
    #pragma unroll
    for (int mt = 0; mt < 4; ++mt) {
      bfx8 af = *(const bfx8*)(w2pk + (((((w << 2) + mt) << 4) + kk) << 9) + (l << 3));
      #pragma unroll
      for (int nt = 0; nt < 2; ++nt)
        acc2[mt][nt] = MFMA(af, xb[nt], acc2[mt][nt]);
    }
  }
  __syncthreads();   // B3 (half0 reads done)

  // ---- pack x half1 (mt 4..7, h 256..511) -> P (zg dead)
  #pragma unroll
  for (int mt = 4; mt < 8; ++mt)
    #pragma unroll
    for (int nt = 0; nt < 2; ++nt) {
      int b = nt * 16 + lr;
      bfx4 p;
      p[0] = f2bf(acc1[mt][nt][0]); p[1] = f2bf(acc1[mt][nt][1]);
      p[2] = f2bf(acc1[mt][nt][2]); p[3] = f2bf(acc1[mt][nt][3]);
      int ch = (w << 3) + ((mt - 4) << 1) + (lg >> 1);
      *(bfx4*)(P + b * 512 + ((ch ^ (b & 7)) << 4) + ((lg & 1) << 3)) = p;
    }
  __syncthreads();   // B4

  // ---- GEMM2b: K = h 256..511 from P ; + b2
  #pragma unroll
  for (int kk = 8; kk < 16; ++kk) {
    bfx8 xb[2];
    #pragma unroll
    for (int nt = 0; nt < 2; ++nt) {
      int b = nt * 16 + lr;
      xb[nt] = *(const bfx8*)(P + b * 512 + (((((kk - 8) << 2) + lg) ^ (b & 7)) << 4));
    }
    #pragma unroll
    for (int mt = 0; mt < 4; ++mt) {
      bfx8 af = *(const bfx8*)(w2pk + (((((w << 2) + mt) << 4) + kk) << 9) + (l << 3));
      #pragma unroll
      for (int nt = 0; nt < 2; ++nt)
        acc2[mt][nt] = MFMA(af, xb[nt], acc2[mt][nt]);
    }
  }
  #pragma unroll
  for (int mt = 0; mt < 4; ++mt) {
    fx4 bz = *(const fx4*)(b2v + n * RH + (w << 6) + mt * 16 + (lg << 2));
    #pragma unroll
    for (int nt = 0; nt < 2; ++nt)
      acc2[mt][nt] += bz;
  }

  // ---- ut*dt fragments (GEMM3 k-tail operand)
  const float dtv = dtp[0];
  bfx8 ufrag[2];
  #pragma unroll
  for (int nt = 0; nt < 2; ++nt) {
    const float* up = ut + (size_t)(b0 + nt * 16 + lr) * UU + (lg << 3);
    float4 u0 = *(const float4*)up;
    float4 u1 = *(const float4*)(up + 4);
    bfx8 v;
    v[0] = f2bf(u0.x * dtv); v[1] = f2bf(u0.y * dtv);
    v[2] = f2bf(u0.z * dtv); v[3] = f2bf(u0.w * dtv);
    v[4] = f2bf(u1.x * dtv); v[5] = f2bf(u1.y * dtv);
    v[6] = f2bf(u1.z * dtv); v[7] = f2bf(u1.w * dtv);
    ufrag[nt] = v;
  }

  // ---- pack g -> Q (Q reads finished at B3; all waves past B4 >= B3)
  #pragma unroll
  for (int mt = 0; mt < 4; ++mt)
    #pragma unroll
    for (int nt = 0; nt < 2; ++nt) {
      int b = nt * 16 + lr;
      bfx4 p;
      p[0] = f2bf(acc2[mt][nt][0]); p[1] = f2bf(acc2[mt][nt][1]);
      p[2] = f2bf(acc2[mt][nt][2]); p[3] = f2bf(acc2[mt][nt][3]);
      int ch = (w << 3) + (mt << 1) + (lg >> 1);
      *(bfx4*)(Q + b * 512 + ((ch ^ (b & 7)) << 4) + ((lg & 1) << 3)) = p;
    }
  __syncthreads();   // B5 (also guarantees GEMM2b reads of P done everywhere)

  // ---- GEMM3: binT[r][b] = rnnB @ [g, ut*dt]^T  (K=288, NKT=9)
  fx4 acc3[4][2];
  #pragma unroll
  for (int mt = 0; mt < 4; ++mt)
    #pragma unroll
    for (int nt = 0; nt < 2; ++nt)
      acc3[mt][nt] = (fx4){0.f, 0.f, 0.f, 0.f};
  {
    const u16* rpk = rnnb + (size_t)n * 73728;
    #pragma unroll
    for (int kk = 0; kk < 8; ++kk) {
      bfx8 gb[2];
      #pragma unroll
      for (int nt = 0; nt < 2; ++nt) {
        int b = nt * 16 + lr;
        gb[nt] = *(const bfx8*)(Q + b * 512 + ((((kk << 2) + lg) ^ (b & 7)) << 4));
      }
      #pragma unroll
      for (int mt = 0; mt < 4; ++mt) {
        bfx8 af = *(const bfx8*)(rpk + (((((w << 2) + mt) * 9) + kk) << 9) + (l << 3));
        #pragma unroll
        for (int nt = 0; nt < 2; ++nt)
          acc3[mt][nt] = MFMA(af, gb[nt], acc3[mt][nt]);
      }
    }
    #pragma unroll
    for (int mt = 0; mt < 4; ++mt) {
      bfx8 af = *(const bfx8*)(rpk + (((((w << 2) + mt) * 9) + 8) << 9) + (l << 3));
      #pragma unroll
      for (int nt = 0; nt < 2; ++nt)
        acc3[mt][nt] = MFMA(af, ufrag[nt], acc3[mt][nt]);
    }
  }

  // ---- pack bin -> P (GEMM2b reads of P finished at B5)
  #pragma unroll
  for (int mt = 0; mt < 4; ++mt)
    #pragma unroll
    for (int nt = 0; nt < 2; ++nt) {
      int b = nt * 16 + lr;
      bfx4 p;
      p[0] = f2bf(acc3[mt][nt][0]); p[1] = f2bf(acc3[mt][nt][1]);
      p[2] = f2bf(acc3[mt][nt][2]); p[3] = f2bf(acc3[mt][nt][3]);
      int ch = (w << 3) + (mt << 1) + (lg >> 1);
      *(bfx4*)(P + b * 512 + ((ch ^ (b & 7)) << 4) + ((lg & 1) << 3)) = p;
    }
  __syncthreads();   // B6

  // ---- write bing in PHYSICAL chunk order (linear copy of P)
  #pragma unroll
  for (int j = 0; j < 4; ++j) {
    int row = (tid >> 5) + (j << 3);
    int c = tid & 31;
    int4 v = *(const int4*)(P + row * 512 + (c << 4));
    *(int4*)(bing + (size_t)(b0 + row) * 2048 + n * 256 + c * 8) = v;
  }
}

// ---------------------------------------------------------------------------
// final v2 [unchanged from R7]: zt1T[d][b] = wot_pk[d][2048] @ bin^T.
// 256 blocks x 512 thr: 64 batch rows x all 256 d. bing k-slices double-
// buffered via global_load_lds + counted vmcnt; yt1 fused in epilogue.
// ---------------------------------------------------------------------------
__global__ __launch_bounds__(512, 2)
void skolr_final(const u16* __restrict__ bing, const u16* __restrict__ wotb,
                 const float* __restrict__ ut, const float* __restrict__ dtp,
                 const float* __restrict__ Cm, const float* __restrict__ Dm,
                 float* __restrict__ outp)
{
  __shared__ __align__(16) char sB[65536];   // 2 x 32KB k-slice buffers
  const int tid = threadIdx.x;
  const int w  = tid >> 6;
  const int l  = tid & 63;
  const int lr = l & 15;
  const int lg = l >> 4;
  const int b0 = blockIdx.x * 64;

  fx4 acc[2][4];
  #pragma unroll
  for (int mt = 0; mt < 2; ++mt)
    #pragma unroll
    for (int nt = 0; nt < 4; ++nt)
      acc[mt][nt] = (fx4){0.f, 0.f, 0.f, 0.f};

  const int srow = tid >> 5;       // 0..15
  const int scol = tid & 31;
  #define STAGE(buf, ks)                                                        \
    {                                                                           \
      _Pragma("unroll")                                                         \
      for (int j = 0; j < 4; ++j) {                                             \
        const u16* src = bing + (size_t)(b0 + j * 16 + srow) * 2048             \
                              + ((ks) << 8) + (scol << 3);                      \
        void* ldst = sB + (buf) * 32768 + (j << 13) + (w << 10);                \
        gload16(src, ldst);                                                     \
      }                                                                         \
    }

  STAGE(0, 0)
  for (int ks = 0; ks < 8; ++ks) {
    if (ks < 7) {
      STAGE((ks + 1) & 1, ks + 1)
      asm volatile("s_waitcnt vmcnt(4)" ::: "memory");
    } else {
      asm volatile("s_waitcnt vmcnt(0)" ::: "memory");
    }
    __builtin_amdgcn_s_barrier();
    const char* cur = sB + (ks & 1) * 32768;
    #pragma unroll
    for (int kk = 0; kk < 8; ++kk) {
      bfx8 bf[4];
      #pragma unroll
      for (int nt = 0; nt < 4; ++nt) {
        int b = nt * 16 + lr;
        bf[nt] = *(const bfx8*)(cur + b * 512 + ((((kk << 2) + lg) ^ (b & 7)) << 4));
      }
      #pragma unroll
      for (int mt = 0; mt < 2; ++mt) {
        bfx8 af = *(const bfx8*)(wotb + (((((w << 1) + mt) << 6) + (ks << 3) + kk) << 9) + (l << 3));
        #pragma unroll
        for (int nt = 0; nt < 4; ++nt)
          acc[mt][nt] = MFMA(af, bf[nt], acc[mt][nt]);
      }
    }
    __builtin_amdgcn_s_barrier();
  }

  // epilogue: zt1 -> global fp32 + bf16 LDS copy for yt1 (reuse sB buf0)
  #pragma unroll
  for (int mt = 0; mt < 2; ++mt)
    #pragma unroll
    for (int nt = 0; nt < 4; ++nt) {
      int bl = nt * 16 + lr;
      int d  = (w << 5) + mt * 16 + (lg << 2);
      *(fx4*)(outp + (size_t)(b0 + bl) * DD + d) = acc[mt][nt];
      bfx4 p;
      p[0] = f2bf(acc[mt][nt][0]); p[1] = f2bf(acc[mt][nt][1]);
      p[2] = f2bf(acc[mt][nt][2]); p[3] = f2bf(acc[mt][nt][3]);
      int chunk5 = d >> 3;
      *(bfx4*)(sB + bl * 512 + ((chunk5 ^ (bl & 7)) << 4) + ((lg & 1) << 3)) = p;
    }
  __syncthreads();

  const float dtv = dtp[0];
  for (int i = tid; i < 64 * NY; i += 512) {
    int b = i / NY;
    int y = i - b * NY;
    float s = 0.f;
    #pragma unroll 4
    for (int dc = 0; dc < 32; ++dc) {
      bfx8 zv = *(const bfx8*)(sB + b * 512 + ((dc ^ (b & 7)) << 4));
      const float* cp = Cm + y * DD + dc * 8;
      float4 c0 = *(const float4*)cp;
      float4 c1 = *(const float4*)(cp + 4);
      float z0 = (float)__builtin_bit_cast(__bf16, (u16)zv[0]);
      float z1 = (float)__builtin_bit_cast(__bf16, (u16)zv[1]);
      float z2 = (float)__builtin_bit_cast(__bf16, (u16)zv[2]);
      float z3 = (float)__builtin_bit_cast(__bf16, (u16)zv[3]);
      float z4 = (float)__builtin_bit_cast(__bf16, (u16)zv[4]);
      float z5 = (float)__builtin_bit_cast(__bf16, (u16)zv[5]);
      float z6 = (float)__builtin_bit_cast(__bf16, (u16)zv[6]);
      float z7 = (float)__builtin_bit_cast(__bf16, (u16)zv[7]);
      s += z0 * c0.x + z1 * c0.y + z2 * c0.z + z3 * c0.w;
      s += z4 * c1.x + z5 * c1.y + z6 * c1.z + z7 * c1.w;
    }
    const float* up = ut + (size_t)(b0 + b) * UU;
    const float* dp = Dm + y * UU;
    float s2 = 0.f;
    #pragma unroll
    for (int u = 0; u < UU; u += 4) {
      float4 uu = *(const float4*)(up + u);
      float4 dd = *(const float4*)(dp + u);
      s2 += uu.x * dd.x + uu.y * dd.y + uu.z * dd.z + uu.w * dd.w;
    }
    outp[(size_t)B_TOT * DD + (size_t)(b0 + b) * NY + y] = s + dtv * s2;
  }
}

// ---------------------------------------------------------------------------
extern "C" void kernel_launch(void* const* d_in, const int* in_sizes, int n_in,
                              void* d_out, int out_size, void* d_ws, size_t ws_size,
                              hipStream_t stream)
{
  (void)in_sizes; (void)n_in; (void)out_size; (void)ws_size;
  const float* zt    = (const float*)d_in[0];
  const float* dtp   = (const float*)d_in[1];
  const float* ut    = (const float*)d_in[2];
  const float* gates = (const float*)d_in[3];
  const float* W1    = (const float*)d_in[4];
  const float* b1    = (const float*)d_in[5];
  const float* lng   = (const float*)d_in[6];
  const float* lnb   = (const float*)d_in[7];
  const float* W2    = (const float*)d_in[8];
  const float* b2    = (const float*)d_in[9];
  // d_in[10]=lam_r, d_in[11]=lam_i unused (h0 = 0 => lambda drops out)
  const float* rnnB  = (const float*)d_in[12];
  const float* Wout  = (const float*)d_in[13];
  const float* Cm    = (const float*)d_in[14];
  const float* Dm    = (const float*)d_in[15];
  float* outp = (float*)d_out;
  char* ws = (char*)d_ws;

  u16* w1g  = (u16*)(ws + 0);           //  2,097,152 B
  u16* w2b  = (u16*)(ws + 2097152);     //  2,097,152 B
  u16* bb   = (u16*)(ws + 4194304);     //  1,179,648 B
  u16* wotb = (u16*)(ws + 5373952);     //  1,048,576 B
  u16* ztb  = (u16*)(ws + 6422528);     //  8,388,608 B
  u16* bing = (u16*)(ws + 14811136);    // 67,108,864 B

  skolr_prep<<<3616, 256, 0, stream>>>(W1, W2, rnnB, Wout, gates, zt,
                                       w1g, w2b, bb, wotb, ztb);
  skolr_fused<<<dim3(8, 512), 256, 0, stream>>>(ztb, dtp, ut, w1g, b1, lng, lnb,
                                                w2b, b2, bb, bing);
  skolr_final<<<256, 512, 0, stream>>>(bing, wotb, ut, dtp, Cm, Dm, outp);
}

// Round 10
// 373.262 us; speedup vs baseline: 1.0409x; 1.0409x over previous
//
#include <hip/hip_runtime.h>
#include <math.h>

#define B_TOT 16384
#define DD    256
#define UU    32
#define NBR   8
#define MH    512
#define RH    256
#define KIN   288
#define NY    20

typedef unsigned short u16;
typedef __attribute__((ext_vector_type(8))) short bfx8;
typedef __attribute__((ext_vector_type(4))) short bfx4;
typedef __attribute__((ext_vector_type(4))) float fx4;

#define MFMA(a, b, c) __builtin_amdgcn_mfma_f32_16x16x32_bf16((a), (b), (c), 0, 0, 0)

__device__ __forceinline__ u16 f2bf(float f) {
  __bf16 h = (__bf16)f;
  return __builtin_bit_cast(u16, h);
}
__device__ __forceinline__ float fsigmoid(float x) {
  return __builtin_amdgcn_rcpf(1.f + __expf(-x));
}
// tanh-form GELU (max |err| vs exact ~3e-4 << bf16 pack noise)
__device__ __forceinline__ float fgelu(float v) {
  float t = v * v;
  float z = v * __builtin_fmaf(t, 0.07135481627f, 1.5957691216f);
  float p = __expf(z);
  return v - v * __builtin_amdgcn_rcpf(p + 1.f);
}
// async global->LDS, 16B/lane; LDS dest wave-uniform base + lane*16
__device__ __forceinline__ void gload16(const void* g, void* l) {
  __builtin_amdgcn_global_load_lds((const __attribute__((address_space(1))) unsigned int*)(g),
                                   (__attribute__((address_space(3))) unsigned int*)(l),
                                   16, 0, 0);
}

// ---------------------------------------------------------------------------
// prep: all weights -> bf16 in MFMA fragment-packed layout:
//   pk[((m_tile*NKT + k_tile)*64 + lane)*8], lane = (m&15) + 16*((k>>3)&3)
// W1 gets sigmoid(gates) folded in; Wout transposed to [d][n*RH+r] then
// packed; ztb plain bf16.   [unchanged]
// ---------------------------------------------------------------------------
__global__ __launch_bounds__(256)
void skolr_prep(const float* __restrict__ W1, const float* __restrict__ W2,
                const float* __restrict__ rnnB, const float* __restrict__ Wout,
                const float* __restrict__ gates, const float* __restrict__ zt,
                u16* __restrict__ w1g, u16* __restrict__ w2b, u16* __restrict__ bb,
                u16* __restrict__ wotb, u16* __restrict__ ztb)
{
  long i = (long)(blockIdx.x * 256 + threadIdx.x) * 8;
  const long E0 = 1048576;   // W1
  const long E1 = 2097152;   // +W2
  const long E2 = 2686976;   // +rnnB
  const long E3 = 3211264;   // +Wout
  const long E4 = 7405568;   // +zt
  if (i >= E4) return;
  if (i < E0) {
    int n = (int)(i >> 17), h = (int)((i >> 8) & 511), d = (int)(i & 255);
    const float* gp = gates + n * DD + d;
    float4 g0 = *(const float4*)gp, g1 = *(const float4*)(gp + 4);
    float4 a = *(const float4*)(W1 + i), b = *(const float4*)(W1 + i + 4);
    bfx8 v;
    v[0] = f2bf(a.x * fsigmoid(g0.x)); v[1] = f2bf(a.y * fsigmoid(g0.y));
    v[2] = f2bf(a.z * fsigmoid(g0.z)); v[3] = f2bf(a.w * fsigmoid(g0.w));
    v[4] = f2bf(b.x * fsigmoid(g1.x)); v[5] = f2bf(b.y * fsigmoid(g1.y));
    v[6] = f2bf(b.z * fsigmoid(g1.z)); v[7] = f2bf(b.w * fsigmoid(g1.w));
    u16* dst = w1g + (size_t)n * 131072
             + ((((h >> 4) << 3) + (d >> 5)) << 9) + ((h & 15) << 3) + (((d >> 3) & 3) << 7);
    *(bfx8*)dst = v;
    return;
  }
  const float* src; u16* dst; long off;
  if (i < E1) {            // W2: [n][r][k], NKT=16
    off = i - E0;
    int n = (int)(off >> 17), r = (int)((off >> 9) & 255), k = (int)(off & 511);
    src = W2 + off;
    dst = w2b + (size_t)n * 131072
        + ((((r >> 4) << 4) + (k >> 5)) << 9) + ((r & 15) << 3) + (((k >> 3) & 3) << 7);
  } else if (i < E2) {     // rnnB: [n][r][k], K=288, NKT=9
    off = i - E1;
    int o = (int)off;
    int n = o / 73728, rem = o - n * 73728;
    int r = rem / KIN, k = rem - r * KIN;
    src = rnnB + off;
    dst = bb + (size_t)n * 73728
        + (((r >> 4) * 9 + (k >> 5)) << 9) + ((r & 15) << 3) + (((k >> 3) & 3) << 7);
  } else if (i < E3) {     // Wout[n][d][r] -> A[d][k=n*256+r], NKT=64
    off = i - E2;
    int n = (int)(off >> 16), rem = (int)(off & 65535);
    int d = rem >> 8, r = rem & 255;
    src = Wout + off;
    dst = wotb + ((((d >> 4) << 6) + (n << 3) + (r >> 5)) << 9)
        + ((d & 15) << 3) + (((r >> 3) & 3) << 7);
  } else {                 // zt plain bf16
    off = i - E3;
    src = zt + off;
    dst = ztb + off;
  }
  float4 a = *(const float4*)src, b = *(const float4*)(src + 4);
  bfx8 v;
  v[0] = f2bf(a.x); v[1] = f2bf(a.y); v[2] = f2bf(a.z); v[3] = f2bf(a.w);
  v[4] = f2bf(b.x); v[5] = f2bf(b.y); v[6] = f2bf(b.z); v[7] = f2bf(b.w);
  *(bfx8*)dst = v;
}

// ---------------------------------------------------------------------------
// fused v3b: 256-thread blocks (4 waves), 32-row batch tile, LDS 33KB.
// ONLY change vs R9: __launch_bounds__(256, 3) -- R9's (256,4) forced a
// 128-reg total budget (~64 arch), spilling the LN/GELU phase (VALU needs
// acc1 in ARCH VGPRs): FETCH 44->157MB, WRITE 64->268MB, MfmaUtil 24->16.5.
// (256,3) gives ~170-reg budget (peak live ~100) -> no spill, >=3 blocks/CU.
// ---------------------------------------------------------------------------
__global__ __launch_bounds__(256, 3)
void skolr_fused(const u16* __restrict__ ztb, const float* __restrict__ dtp,
                 const float* __restrict__ ut,
                 const u16* __restrict__ w1g, const float* __restrict__ b1,
                 const float* __restrict__ lng, const float* __restrict__ lnb,
                 const u16* __restrict__ w2g, const float* __restrict__ b2v,
                 const u16* __restrict__ rnnb, u16* __restrict__ bing)
{
  __shared__ __align__(16) char smX[32768];     // P | Q
  __shared__ __align__(16) float smR[256];      // LN partials [2][4][32]
  const int tid = threadIdx.x;
  const int w  = tid >> 6;       // 0..3
  const int l  = tid & 63;
  const int lr = l & 15;
  const int lg = l >> 4;
  const int n  = blockIdx.x;     // branch -> XCD (linear%8)
  const int b0 = blockIdx.y * 32;
  char* P = smX;
  char* Q = smX + 16384;

  // ---- S0: stage zg tile (32 rows x 512B) -> P, swizzled via source addr
  #pragma unroll
  for (int j = 0; j < 4; ++j) {
    int q = (j << 2) + w;              // 0..15, each covers rows 2q,2q+1
    int r = (q << 1) + (l >> 5);
    const u16* src = ztb + (size_t)(b0 + r) * DD + (((l & 31) ^ (r & 7)) << 3);
    gload16(src, P + (q << 10));
  }
  __syncthreads();   // S0

  // ---- GEMM1: xT[h][b] = W1'[n] @ zg^T  (M=512, N=32, K=256)
  // wave w owns h rows [w*64, w*64+64) (mt 0..3) and [256+w*64, ...) (mt 4..7)
  fx4 acc1[8][2];
  #pragma unroll
  for (int mt = 0; mt < 8; ++mt)
    #pragma unroll
    for (int nt = 0; nt < 2; ++nt)
      acc1[mt][nt] = (fx4){0.f, 0.f, 0.f, 0.f};
  {
    const u16* w1pk = w1g + (size_t)n * 131072;
    #pragma unroll
    for (int kk = 0; kk < 8; ++kk) {
      bfx8 bfr[2];
      #pragma unroll
      for (int nt = 0; nt < 2; ++nt) {
        int b = nt * 16 + lr;
        bfr[nt] = *(const bfx8*)(P + b * 512 + ((((kk << 2) + lg) ^ (b & 7)) << 4));
      }
      #pragma unroll
      for (int mt = 0; mt < 8; ++mt) {
        int mtile = (mt < 4 ? (w << 2) + mt : 16 + (w << 2) + (mt - 4));
        bfx8 af = *(const bfx8*)(w1pk + (((mtile << 3) + kk) << 9) + (l << 3));
        #pragma unroll
        for (int nt = 0; nt < 2; ++nt)
          acc1[mt][nt] = MFMA(af, bfr[nt], acc1[mt][nt]);
      }
    }
  }
  #pragma unroll
  for (int mt = 0; mt < 8; ++mt) {
    int hb = (mt < 4 ? (w << 6) + mt * 16 : 256 + (w << 6) + (mt - 4) * 16) + (lg << 2);
    fx4 bv = *(const fx4*)(b1 + n * MH + hb);
    #pragma unroll
    for (int nt = 0; nt < 2; ++nt)
      acc1[mt][nt] += bv;
  }

  // ---- LN partials (each wave covers 128 of the 512 h rows)
  #pragma unroll
  for (int nt = 0; nt < 2; ++nt) {
    float s1 = 0.f, s2 = 0.f;
    #pragma unroll
    for (int mt = 0; mt < 8; ++mt)
      #pragma unroll
      for (int r = 0; r < 4; ++r) { float v = acc1[mt][nt][r]; s1 += v; s2 += v * v; }
    s1 += __shfl_xor(s1, 16); s1 += __shfl_xor(s1, 32);
    s2 += __shfl_xor(s2, 16); s2 += __shfl_xor(s2, 32);
    if (l < 16) { smR[(w << 5) + nt * 16 + l] = s1; smR[128 + (w << 5) + nt * 16 + l] = s2; }
  }
  __syncthreads();   // B1 (also: GEMM1 reads of P done)

  // ---- stats (redundant per-thread) + LN + GELU in regs
  float meanv[2], rstdv[2];
  #pragma unroll
  for (int nt = 0; nt < 2; ++nt) {
    float ms = 0.f, ss = 0.f;
    #pragma unroll
    for (int wv = 0; wv < 4; ++wv) {
      ms += smR[(wv << 5) + nt * 16 + lr];
      ss += smR[128 + (wv << 5) + nt * 16 + lr];
    }
    float mean = ms * (1.f / 512.f);
    meanv[nt] = mean;
    rstdv[nt] = rsqrtf(ss * (1.f / 512.f) - mean * mean + 1e-5f);
  }
  #pragma unroll
  for (int mt = 0; mt < 8; ++mt) {
    int hb = (mt < 4 ? (w << 6) + mt * 16 : 256 + (w << 6) + (mt - 4) * 16) + (lg << 2);
    fx4 g4 = *(const fx4*)(lng + n * MH + hb);
    fx4 e4 = *(const fx4*)(lnb + n * MH + hb);
    #pragma unroll
    for (int nt = 0; nt < 2; ++nt)
      #pragma unroll
      for (int r = 0; r < 4; ++r) {
        float v = (acc1[mt][nt][r] - meanv[nt]) * rstdv[nt] * g4[r] + e4[r];
        acc1[mt][nt][r] = fgelu(v);
      }
  }

  // ---- pack x half0 (mt 0..3, h 0..255) -> Q [b][512B], XOR ^(b&7)
  #pragma unroll
  for (int mt = 0; mt < 4; ++mt)
    #pragma unroll
    for (int nt = 0; nt < 2; ++nt) {
      int b = nt * 16 + lr;
      bfx4 p;
      p[0] = f2bf(acc1[mt][nt][0]); p[1] = f2bf(acc1[mt][nt][1]);
      p[2] = f2bf(acc1[mt][nt][2]); p[3] = f2bf(acc1[mt][nt][3]);
      int ch = (w << 3) + (mt << 1) + (lg >> 1);
      *(bfx4*)(Q + b * 512 + ((ch ^ (b & 7)) << 4) + ((lg & 1) << 3)) = p;
    }
  __syncthreads();   // B2

  // ---- GEMM2a: gT[r][b], K = h 0..255 from Q
  fx4 acc2[4][2];
  #pragma unroll
  for (int mt = 0; mt < 4; ++mt)
    #pragma unroll
    for (int nt = 0; nt < 2; ++nt)
      acc2[mt][nt] = (fx4){0.f, 0.f, 0.f, 0.f};
  const u16* w2pk = w2g + (size_t)n * 131072;
  #pragma unroll
  for (int kk = 0; kk < 8; ++kk) {
    bfx8 xb[2];
    #pragma unroll
    for (int nt = 0; nt < 2; ++nt) {
      int b = nt * 16 + lr;
      xb[nt] = *(const bfx8*)(Q + b * 512 + ((((kk << 2) + lg) ^ (b & 7)) << 4));
    }
    #pragma unroll
    for (int mt = 0; mt < 4; ++mt) {
      bfx8 af = *(const bfx8*)(w2pk + (((((w << 2) + mt) << 4) + kk) << 9) + (l << 3));
      #pragma unroll
      for (int nt = 0; nt < 2; ++nt)
        acc2[mt][nt] = MFMA(af, xb[nt], acc2[mt][nt]);
    }
  }
  __syncthreads();   // B3 (half0 reads done)

  // ---- pack x half1 (mt 4..7, h 256..511) -> P (zg dead)
  #pragma unroll
  for (int mt = 4; mt < 8; ++mt)
    #pragma unroll
    for (int nt = 0; nt < 2; ++nt) {
      int b = nt * 16 + lr;
      bfx4 p;
      p[0] = f2bf(acc1[mt][nt][0]); p[1] = f2bf(acc1[mt][nt][1]);
      p[2] = f2bf(acc1[mt][nt][2]); p[3] = f2bf(acc1[mt][nt][3]);
      int ch = (w << 3) + ((mt - 4) << 1) + (lg >> 1);
      *(bfx4*)(P + b * 512 + ((ch ^ (b & 7)) << 4) + ((lg & 1) << 3)) = p;
    }
  __syncthreads();   // B4

  // ---- GEMM2b: K = h 256..511 from P ; + b2
  #pragma unroll
  for (int kk = 8; kk < 16; ++kk) {
    bfx8 xb[2];
    #pragma unroll
    for (int nt = 0; nt < 2; ++nt) {
      int b = nt * 16 + lr;
      xb[nt] = *(const bfx8*)(P + b * 512 + (((((kk - 8) << 2) + lg) ^ (b & 7)) << 4));
    }
    #pragma unroll
    for (int mt = 0; mt < 4; ++mt) {
      bfx8 af = *(const bfx8*)(w2pk + (((((w << 2) + mt) << 4) + kk) << 9) + (l << 3));
      #pragma unroll
      for (int nt = 0; nt < 2; ++nt)
        acc2[mt][nt] = MFMA(af, xb[nt], acc2[mt][nt]);
    }
  }
  #pragma unroll
  for (int mt = 0; mt < 4; ++mt) {
    fx4 bz = *(const fx4*)(b2v + n * RH + (w << 6) + mt * 16 + (lg << 2));
    #pragma unroll
    for (int nt = 0; nt < 2; ++nt)
      acc2[mt][nt] += bz;
  }

  // ---- ut*dt fragments (GEMM3 k-tail operand)
  const float dtv = dtp[0];
  bfx8 ufrag[2];
  #pragma unroll
  for (int nt = 0; nt < 2; ++nt) {
    const float* up = ut + (size_t)(b0 + nt * 16 + lr) * UU + (lg << 3);
    float4 u0 = *(const float4*)up;
    float4 u1 = *(const float4*)(up + 4);
    bfx8 v;
    v[0] = f2bf(u0.x * dtv); v[1] = f2bf(u0.y * dtv);
    v[2] = f2bf(u0.z * dtv); v[3] = f2bf(u0.w * dtv);
    v[4] = f2bf(u1.x * dtv); v[5] = f2bf(u1.y * dtv);
    v[6] = f2bf(u1.z * dtv); v[7] = f2bf(u1.w * dtv);
    ufrag[nt] = v;
  }

  // ---- pack g -> Q (Q reads finished at B3; all waves past B4 >= B3)
  #pragma unroll
  for (int mt = 0; mt < 4; ++mt)
    #pragma unroll
    for (int nt = 0; nt < 2; ++nt) {
      int b = nt * 16 + lr;
      bfx4 p;
      p[0] = f2bf(acc2[mt][nt][0]); p[1] = f2bf(acc2[mt][nt][1]);
      p[2] = f2bf(acc2[mt][nt][2]); p[3] = f2bf(acc2[mt][nt][3]);
      int ch = (w << 3) + (mt << 1) + (lg >> 1);
      *(bfx4*)(Q + b * 512 + ((ch ^ (b & 7)) << 4) + ((lg & 1) << 3)) = p;
    }
  __syncthreads();   // B5 (also guarantees GEMM2b reads of P done everywhere)

  // ---- GEMM3: binT[r][b] = rnnB @ [g, ut*dt]^T  (K=288, NKT=9)
  fx4 acc3[4][2];
  #pragma unroll
  for (int mt = 0; mt < 4; ++mt)
    #pragma unroll
    for (int nt = 0; nt < 2; ++nt)
      acc3[mt][nt] = (fx4){0.f, 0.f, 0.f, 0.f};
  {
    const u16* rpk = rnnb + (size_t)n * 73728;
    #pragma unroll
    for (int kk = 0; kk < 8; ++kk) {
      bfx8 gb[2];
      #pragma unroll
      for (int nt = 0; nt < 2; ++nt) {
        int b = nt * 16 + lr;
        gb[nt] = *(const bfx8*)(Q + b * 512 + ((((kk << 2) + lg) ^ (b & 7)) << 4));
      }
      #pragma unroll
      for (int mt = 0; mt < 4; ++mt) {
        bfx8 af = *(const bfx8*)(rpk + (((((w << 2) + mt) * 9) + kk) << 9) + (l << 3));
        #pragma unroll
        for (int nt = 0; nt < 2; ++nt)
          acc3[mt][nt] = MFMA(af, gb[nt], acc3[mt][nt]);
      }
    }
    #pragma unroll
    for (int mt = 0; mt < 4; ++mt) {
      bfx8 af = *(const bfx8*)(rpk + (((((w << 2) + mt) * 9) + 8) << 9) + (l << 3));
      #pragma unroll
      for (int nt = 0; nt < 2; ++nt)
        acc3[mt][nt] = MFMA(af, ufrag[nt], acc3[mt][nt]);
    }
  }

  // ---- pack bin -> P (GEMM2b reads of P finished at B5)
  #pragma unroll
  for (int mt = 0; mt < 4; ++mt)
    #pragma unroll
    for (int nt = 0; nt < 2; ++nt) {
      int b = nt * 16 + lr;
      bfx4 p;
      p[0] = f2bf(acc3[mt][nt][0]); p[1] = f2bf(acc3[mt][nt][1]);
      p[2] = f2bf(acc3[mt][nt][2]); p[3] = f2bf(acc3[mt][nt][3]);
      int ch = (w << 3) + (mt << 1) + (lg >> 1);
      *(bfx4*)(P + b * 512 + ((ch ^ (b & 7)) << 4) + ((lg & 1) << 3)) = p;
    }
  __syncthreads();   // B6

  // ---- write bing in PHYSICAL chunk order (linear copy of P)
  #pragma unroll
  for (int j = 0; j < 4; ++j) {
    int row = (tid >> 5) + (j << 3);
    int c = tid & 31;
    int4 v = *(const int4*)(P + row * 512 + (c << 4));
    *(int4*)(bing + (size_t)(b0 + row) * 2048 + n * 256 + c * 8) = v;
  }
}

// ---------------------------------------------------------------------------
// final v2 [unchanged]: zt1T[d][b] = wot_pk[d][2048] @ bin^T.
// 256 blocks x 512 thr: 64 batch rows x all 256 d. bing k-slices double-
// buffered via global_load_lds + counted vmcnt; yt1 fused in epilogue.
// ---------------------------------------------------------------------------
__global__ __launch_bounds__(512, 2)
void skolr_final(const u16* __restrict__ bing, const u16* __restrict__ wotb,
                 const float* __restrict__ ut, const float* __restrict__ dtp,
                 const float* __restrict__ Cm, const float* __restrict__ Dm,
                 float* __restrict__ outp)
{
  __shared__ __align__(16) char sB[65536];   // 2 x 32KB k-slice buffers
  const int tid = threadIdx.x;
  const int w  = tid >> 6;
  const int l  = tid & 63;
  const int lr = l & 15;
  const int lg = l >> 4;
  const int b0 = blockIdx.x * 64;

  fx4 acc[2][4];
  #pragma unroll
  for (int mt = 0; mt < 2; ++mt)
    #pragma unroll
    for (int nt = 0; nt < 4; ++nt)
      acc[mt][nt] = (fx4){0.f, 0.f, 0.f, 0.f};

  const int srow = tid >> 5;       // 0..15
  const int scol = tid & 31;
  #define STAGE(buf, ks)                                                        \
    {                                                                           \
      _Pragma("unroll")                                                         \
      for (int j = 0; j < 4; ++j) {                                             \
        const u16* src = bing + (size_t)(b0 + j * 16 + srow) * 2048             \
                              + ((ks) << 8) + (scol << 3);                      \
        void* ldst = sB + (buf) * 32768 + (j << 13) + (w << 10);                \
        gload16(src, ldst);                                                     \
      }                                                                         \
    }

  STAGE(0, 0)
  for (int ks = 0; ks < 8; ++ks) {
    if (ks < 7) {
      STAGE((ks + 1) & 1, ks + 1)
      asm volatile("s_waitcnt vmcnt(4)" ::: "memory");
    } else {
      asm volatile("s_waitcnt vmcnt(0)" ::: "memory");
    }
    __builtin_amdgcn_s_barrier();
    const char* cur = sB + (ks & 1) * 32768;
    #pragma unroll
    for (int kk = 0; kk < 8; ++kk) {
      bfx8 bf[4];
      #pragma unroll
      for (int nt = 0; nt < 4; ++nt) {
        int b = nt * 16 + lr;
        bf[nt] = *(const bfx8*)(cur + b * 512 + ((((kk << 2) + lg) ^ (b & 7)) << 4));
      }
      #pragma unroll
      for (int mt = 0; mt < 2; ++mt) {
        bfx8 af = *(const bfx8*)(wotb + (((((w << 1) + mt) << 6) + (ks << 3) + kk) << 9) + (l << 3));
        #pragma unroll
        for (int nt = 0; nt < 4; ++nt)
          acc[mt][nt] = MFMA(af, bf[nt], acc[mt][nt]);
      }
    }
    __builtin_amdgcn_s_barrier();
  }

  // epilogue: zt1 -> global fp32 + bf16 LDS copy for yt1 (reuse sB buf0)
  #pragma unroll
  for (int mt = 0; mt < 2; ++mt)
    #pragma unroll
    for (int nt = 0; nt < 4; ++nt) {
      int bl = nt * 16 + lr;
      int d  = (w << 5) + mt * 16 + (lg << 2);
      *(fx4*)(outp + (size_t)(b0 + bl) * DD + d) = acc[mt][nt];
      bfx4 p;
      p[0] = f2bf(acc[mt][nt][0]); p[1] = f2bf(acc[mt][nt][1]);
      p[2] = f2bf(acc[mt][nt][2]); p[3] = f2bf(acc[mt][nt][3]);
      int chunk5 = d >> 3;
      *(bfx4*)(sB + bl * 512 + ((chunk5 ^ (bl & 7)) << 4) + ((lg & 1) << 3)) = p;
    }
  __syncthreads();

  const float dtv = dtp[0];
  for (int i = tid; i < 64 * NY; i += 512) {
    int b = i / NY;
    int y = i - b * NY;
    float s = 0.f;
    #pragma unroll 4
    for (int dc = 0; dc < 32; ++dc) {
      bfx8 zv = *(const bfx8*)(sB + b * 512 + ((dc ^ (b & 7)) << 4));
      const float* cp = Cm + y * DD + dc * 8;
      float4 c0 = *(const float4*)cp;
      float4 c1 = *(const float4*)(cp + 4);
      float z0 = (float)__builtin_bit_cast(__bf16, (u16)zv[0]);
      float z1 = (float)__builtin_bit_cast(__bf16, (u16)zv[1]);
      float z2 = (float)__builtin_bit_cast(__bf16, (u16)zv[2]);
      float z3 = (float)__builtin_bit_cast(__bf16, (u16)zv[3]);
      float z4 = (float)__builtin_bit_cast(__bf16, (u16)zv[4]);
      float z5 = (float)__builtin_bit_cast(__bf16, (u16)zv[5]);
      float z6 = (float)__builtin_bit_cast(__bf16, (u16)zv[6]);
      float z7 = (float)__builtin_bit_cast(__bf16, (u16)zv[7]);
      s += z0 * c0.x + z1 * c0.y + z2 * c0.z + z3 * c0.w;
      s += z4 * c1.x + z5 * c1.y + z6 * c1.z + z7 * c1.w;
    }
    const float* up = ut + (size_t)(b0 + b) * UU;
    const float* dp = Dm + y * UU;
    float s2 = 0.f;
    #pragma unroll
    for (int u = 0; u < UU; u += 4) {
      float4 uu = *(const float4*)(up + u);
      float4 dd = *(const float4*)(dp + u);
      s2 += uu.x * dd.x + uu.y * dd.y + uu.z * dd.z + uu.w * dd.w;
    }
    outp[(size_t)B_TOT * DD + (size_t)(b0 + b) * NY + y] = s + dtv * s2;
  }
}

// ---------------------------------------------------------------------------
extern "C" void kernel_launch(void* const* d_in, const int* in_sizes, int n_in,
                              void* d_out, int out_size, void* d_ws, size_t ws_size,
                              hipStream_t stream)
{
  (void)in_sizes; (void)n_in; (void)out_size; (void)ws_size;
  const float* zt    = (const float*)d_in[0];
  const float* dtp   = (const float*)d_in[1];
  const float* ut    = (const float*)d_in[2];
  const float* gates = (const float*)d_in[3];
  const float* W1    = (const float*)d_in[4];
  const float* b1    = (const float*)d_in[5];
  const float* lng   = (const float*)d_in[6];
  const float* lnb   = (const float*)d_in[7];
  const float* W2    = (const float*)d_in[8];
  const float* b2    = (const float*)d_in[9];
  // d_in[10]=lam_r, d_in[11]=lam_i unused (h0 = 0 => lambda drops out)
  const float* rnnB  = (const float*)d_in[12];
  const float* Wout  = (const float*)d_in[13];
  const float* Cm    = (const float*)d_in[14];
  const float* Dm    = (const float*)d_in[15];
  float* outp = (float*)d_out;
  char* ws = (char*)d_ws;

  u16* w1g  = (u16*)(ws + 0);           //  2,097,152 B
  u16* w2b  = (u16*)(ws + 2097152);     //  2,097,152 B
  u16* bb   = (u16*)(ws + 4194304);     //  1,179,648 B
  u16* wotb = (u16*)(ws + 5373952);     //  1,048,576 B
  u16* ztb  = (u16*)(ws + 6422528);     //  8,388,608 B
  u16* bing = (u16*)(ws + 14811136);    // 67,108,864 B

  skolr_prep<<<3616, 256, 0, stream>>>(W1, W2, rnnB, Wout, gates, zt,
                                       w1g, w2b, bb, wotb, ztb);
  skolr_fused<<<dim3(8, 512), 256, 0, stream>>>(ztb, dtp, ut, w1g, b1, lng, lnb,
                                                w2b, b2, bb, bing);
  skolr_final<<<256, 512, 0, stream>>>(bing, wotb, ut, dtp, Cm, Dm, outp);
}

// Round 11
// 307.582 us; speedup vs baseline: 1.2631x; 1.2135x over previous
//
#include <hip/hip_runtime.h>
#include <math.h>

#define B_TOT 16384
#define DD    256
#define UU    32
#define NBR   8
#define MH    512
#define RH    256
#define KIN   288
#define NY    20

typedef unsigned short u16;
typedef __attribute__((ext_vector_type(8))) short bfx8;
typedef __attribute__((ext_vector_type(4))) short bfx4;
typedef __attribute__((ext_vector_type(4))) float fx4;

#define MFMA(a, b, c) __builtin_amdgcn_mfma_f32_16x16x32_bf16((a), (b), (c), 0, 0, 0)

__device__ __forceinline__ u16 f2bf(float f) {
  __bf16 h = (__bf16)f;
  return __builtin_bit_cast(u16, h);
}
__device__ __forceinline__ float bf2f(u16 u) {
  union { unsigned u; float f; } v; v.u = ((unsigned)u) << 16;
  return v.f;
}
__device__ __forceinline__ float fsigmoid(float x) {
  return __builtin_amdgcn_rcpf(1.f + __expf(-x));
}
// tanh-form GELU (max |err| vs exact ~3e-4 << bf16 pack noise)
__device__ __forceinline__ float fgelu(float v) {
  float t = v * v;
  float z = v * __builtin_fmaf(t, 0.07135481627f, 1.5957691216f);
  float p = __expf(z);
  return v - v * __builtin_amdgcn_rcpf(p + 1.f);
}
// async global->LDS, 16B/lane; LDS dest wave-uniform base + lane*16
__device__ __forceinline__ void gload16(const void* g, void* l) {
  __builtin_amdgcn_global_load_lds((const __attribute__((address_space(1))) unsigned int*)(g),
                                   (__attribute__((address_space(3))) unsigned int*)(l),
                                   16, 0, 0);
}

// ---------------------------------------------------------------------------
// prep: all weights -> bf16 in MFMA fragment-packed layout:
//   pk[((m_tile*NKT + k_tile)*64 + lane)*8], lane = (m&15) + 16*((k>>3)&3)
// W1 gets sigmoid(gates) folded in; Wout packed PER BRANCH as A[d][k=r]
// (NKT=8, 64K u16/branch); ztb plain bf16.
// ---------------------------------------------------------------------------
__global__ __launch_bounds__(256)
void skolr_prep(const float* __restrict__ W1, const float* __restrict__ W2,
                const float* __restrict__ rnnB, const float* __restrict__ Wout,
                const float* __restrict__ gates, const float* __restrict__ zt,
                u16* __restrict__ w1g, u16* __restrict__ w2b, u16* __restrict__ bb,
                u16* __restrict__ wotb, u16* __restrict__ ztb)
{
  long i = (long)(blockIdx.x * 256 + threadIdx.x) * 8;
  const long E0 = 1048576;   // W1
  const long E1 = 2097152;   // +W2
  const long E2 = 2686976;   // +rnnB
  const long E3 = 3211264;   // +Wout
  const long E4 = 7405568;   // +zt
  if (i >= E4) return;
  if (i < E0) {
    int n = (int)(i >> 17), h = (int)((i >> 8) & 511), d = (int)(i & 255);
    const float* gp = gates + n * DD + d;
    float4 g0 = *(const float4*)gp, g1 = *(const float4*)(gp + 4);
    float4 a = *(const float4*)(W1 + i), b = *(const float4*)(W1 + i + 4);
    bfx8 v;
    v[0] = f2bf(a.x * fsigmoid(g0.x)); v[1] = f2bf(a.y * fsigmoid(g0.y));
    v[2] = f2bf(a.z * fsigmoid(g0.z)); v[3] = f2bf(a.w * fsigmoid(g0.w));
    v[4] = f2bf(b.x * fsigmoid(g1.x)); v[5] = f2bf(b.y * fsigmoid(g1.y));
    v[6] = f2bf(b.z * fsigmoid(g1.z)); v[7] = f2bf(b.w * fsigmoid(g1.w));
    u16* dst = w1g + (size_t)n * 131072
             + ((((h >> 4) << 3) + (d >> 5)) << 9) + ((h & 15) << 3) + (((d >> 3) & 3) << 7);
    *(bfx8*)dst = v;
    return;
  }
  const float* src; u16* dst; long off;
  if (i < E1) {            // W2: [n][r][k], NKT=16
    off = i - E0;
    int n = (int)(off >> 17), r = (int)((off >> 9) & 255), k = (int)(off & 511);
    src = W2 + off;
    dst = w2b + (size_t)n * 131072
        + ((((r >> 4) << 4) + (k >> 5)) << 9) + ((r & 15) << 3) + (((k >> 3) & 3) << 7);
  } else if (i < E2) {     // rnnB: [n][r][k], K=288, NKT=9
    off = i - E1;
    int o = (int)off;
    int n = o / 73728, rem = o - n * 73728;
    int r = rem / KIN, k = rem - r * KIN;
    src = rnnB + off;
    dst = bb + (size_t)n * 73728
        + (((r >> 4) * 9 + (k >> 5)) << 9) + ((r & 15) << 3) + (((k >> 3) & 3) << 7);
  } else if (i < E3) {     // Wout[n][d][r] -> per-branch A[d][k=r], NKT=8
    off = i - E2;
    int n = (int)(off >> 16), rem = (int)(off & 65535);
    int d = rem >> 8, r = rem & 255;
    src = Wout + off;
    dst = wotb + (size_t)n * 65536
        + ((((d >> 4) << 3) + (r >> 5)) << 9) + ((d & 15) << 3) + (((r >> 3) & 3) << 7);
  } else {                 // zt plain bf16
    off = i - E3;
    src = zt + off;
    dst = ztb + off;
  }
  float4 a = *(const float4*)src, b = *(const float4*)(src + 4);
  bfx8 v;
  v[0] = f2bf(a.x); v[1] = f2bf(a.y); v[2] = f2bf(a.z); v[3] = f2bf(a.w);
  v[4] = f2bf(b.x); v[5] = f2bf(b.y); v[6] = f2bf(b.z); v[7] = f2bf(b.w);
  *(bfx8*)dst = v;
}

// ---------------------------------------------------------------------------
// fused stages 1-4 per (branch n -> XCD, 64-row batch tile).  [R5 structure,
// proven 158us, + GEMM4 appended]
// zt1 partial (this branch) written bf16 to zt1p plane n in PHYSICAL
// (swizzled) chunk order; skolr_reduce_y sums the 8 planes.
// bin never touches HBM. 2 blocks/CU (VGPR~80 needs 128 quantum; LDS 68KB).
// ---------------------------------------------------------------------------
__global__ __launch_bounds__(512, 2)
void skolr_fused(const u16* __restrict__ ztb, const float* __restrict__ dtp,
                 const float* __restrict__ ut,
                 const u16* __restrict__ w1g, const float* __restrict__ b1,
                 const float* __restrict__ lng, const float* __restrict__ lnb,
                 const u16* __restrict__ w2g, const float* __restrict__ b2v,
                 const u16* __restrict__ rnnb, const u16* __restrict__ wotpk,
                 u16* __restrict__ zt1p)
{
  __shared__ __align__(16) char smX[65536];
  __shared__ __align__(16) float smR[1024];
  const int tid = threadIdx.x;
  const int w  = tid >> 6;
  const int l  = tid & 63;
  const int lr = l & 15;
  const int lg = l >> 4;
  const int n  = blockIdx.x;      // branch -> XCD
  const int b0 = blockIdx.y * 64;

  // ---- S0: stage ztb tile 64x512B -> smX[0:32K], swizzled via source addr
  #pragma unroll
  for (int j = 0; j < 4; ++j) {
    int q = (w << 2) + j;             // 0..31
    int r = (q << 1) + (l >> 5);
    const u16* src = ztb + (size_t)(b0 + r) * DD + (((l & 31) ^ (r & 7)) << 3);
    gload16(src, smX + (q << 10));
  }
  __syncthreads();   // S0

  // ---- GEMM1: xT[h][b] = W1'[n] @ zg^T  (M=512, N=64, K=256)
  fx4 acc1[4][4];
  #pragma unroll
  for (int mt = 0; mt < 4; ++mt)
    #pragma unroll
    for (int nt = 0; nt < 4; ++nt)
      acc1[mt][nt] = (fx4){0.f, 0.f, 0.f, 0.f};
  {
    const u16* w1pk = w1g + (size_t)n * 131072;
    #pragma unroll
    for (int kk = 0; kk < 8; ++kk) {
      bfx8 bfr[4];
      #pragma unroll
      for (int nt = 0; nt < 4; ++nt) {
        int b = nt * 16 + lr;
        bfr[nt] = *(const bfx8*)(smX + b * 512 + ((((kk << 2) + lg) ^ (b & 7)) << 4));
      }
      #pragma unroll
      for (int mt = 0; mt < 4; ++mt) {
        int mtile = (mt < 2 ? (w << 1) + mt : 16 + (w << 1) + (mt - 2));
        bfx8 af = *(const bfx8*)(w1pk + (((mtile << 3) + kk) << 9) + (l << 3));
        #pragma unroll
        for (int nt = 0; nt < 4; ++nt)
          acc1[mt][nt] = MFMA(af, bfr[nt], acc1[mt][nt]);
      }
    }
  }
  #pragma unroll
  for (int mt = 0; mt < 4; ++mt) {
    int hb = (mt < 2 ? (w << 5) + mt * 16 : 256 + (w << 5) + (mt - 2) * 16) + (lg << 2);
    fx4 bv = *(const fx4*)(b1 + n * MH + hb);
    #pragma unroll
    for (int nt = 0; nt < 4; ++nt)
      acc1[mt][nt] += bv;
  }

  // ---- LN partials
  #pragma unroll
  for (int nt = 0; nt < 4; ++nt) {
    float s1 = 0.f, s2 = 0.f;
    #pragma unroll
    for (int mt = 0; mt < 4; ++mt)
      #pragma unroll
      for (int r = 0; r < 4; ++r) { float v = acc1[mt][nt][r]; s1 += v; s2 += v * v; }
    s1 += __shfl_xor(s1, 16); s1 += __shfl_xor(s1, 32);
    s2 += __shfl_xor(s2, 16); s2 += __shfl_xor(s2, 32);
    if (l < 16) { smR[w * 64 + nt * 16 + l] = s1; smR[512 + w * 64 + nt * 16 + l] = s2; }
  }
  __syncthreads();   // B1

  // ---- stats (redundant per-thread) + LN + GELU + pack x -> smX[0:64K]
  float meanv[4], rstdv[4];
  #pragma unroll
  for (int nt = 0; nt < 4; ++nt) {
    float ms = 0.f, ss = 0.f;
    #pragma unroll
    for (int wv = 0; wv < 8; ++wv) {
      ms += smR[wv * 64 + nt * 16 + lr];
      ss += smR[512 + wv * 64 + nt * 16 + lr];
    }
    float mean = ms * (1.f / 512.f);
    meanv[nt] = mean;
    rstdv[nt] = rsqrtf(ss * (1.f / 512.f) - mean * mean + 1e-5f);
  }
  #pragma unroll
  for (int mt = 0; mt < 4; ++mt) {
    int htile = (mt < 2 ? (w << 5) + mt * 16 : 256 + (w << 5) + (mt - 2) * 16);
    int hb = htile + (lg << 2);
    fx4 g4 = *(const fx4*)(lng + n * MH + hb);
    fx4 e4 = *(const fx4*)(lnb + n * MH + hb);
    #pragma unroll
    for (int nt = 0; nt < 4; ++nt) {
      #pragma unroll
      for (int r = 0; r < 4; ++r) {
        float v = (acc1[mt][nt][r] - meanv[nt]) * rstdv[nt] * g4[r] + e4[r];
        acc1[mt][nt][r] = fgelu(v);
      }
      int b = nt * 16 + lr;
      bfx4 p;
      p[0] = f2bf(acc1[mt][nt][0]); p[1] = f2bf(acc1[mt][nt][1]);
      p[2] = f2bf(acc1[mt][nt][2]); p[3] = f2bf(acc1[mt][nt][3]);
      int chunk6 = (htile >> 3) + (lg >> 1);
      *(bfx4*)(smX + b * 1024 + ((chunk6 ^ (b & 7)) << 4) + ((lg & 1) << 3)) = p;
    }
  }
  __syncthreads();   // B2

  // ---- GEMM2: gT[r][b] = W2[n] @ x^T  (K=512)
  const int r0 = w << 5;
  fx4 acc2[2][4];
  #pragma unroll
  for (int mt = 0; mt < 2; ++mt)
    #pragma unroll
    for (int nt = 0; nt < 4; ++nt)
      acc2[mt][nt] = (fx4){0.f, 0.f, 0.f, 0.f};
  {
    const u16* w2pk = w2g + (size_t)n * 131072;
    #pragma unroll
    for (int kk = 0; kk < 16; ++kk) {
      bfx8 xb[4];
      #pragma unroll
      for (int nt = 0; nt < 4; ++nt) {
        int b = nt * 16 + lr;
        xb[nt] = *(const bfx8*)(smX + b * 1024 + ((((kk << 2) + lg) ^ (b & 7)) << 4));
      }
      #pragma unroll
      for (int mt = 0; mt < 2; ++mt) {
        bfx8 af = *(const bfx8*)(w2pk + (((((w << 1) + mt) << 4) + kk) << 9) + (l << 3));
        #pragma unroll
        for (int nt = 0; nt < 4; ++nt)
          acc2[mt][nt] = MFMA(af, xb[nt], acc2[mt][nt]);
      }
    }
  }
  #pragma unroll
  for (int mt = 0; mt < 2; ++mt) {
    fx4 bz = *(const fx4*)(b2v + n * RH + r0 + mt * 16 + (lg << 2));
    #pragma unroll
    for (int nt = 0; nt < 4; ++nt)
      acc2[mt][nt] += bz;
  }
  __syncthreads();   // B3

  // ---- pack g -> smX[0:32K] ([b][512B], ^(b&7))
  #pragma unroll
  for (int mt = 0; mt < 2; ++mt)
    #pragma unroll
    for (int nt = 0; nt < 4; ++nt) {
      int b = nt * 16 + lr;
      bfx4 p;
      p[0] = f2bf(acc2[mt][nt][0]); p[1] = f2bf(acc2[mt][nt][1]);
      p[2] = f2bf(acc2[mt][nt][2]); p[3] = f2bf(acc2[mt][nt][3]);
      int chunk5 = ((r0 + mt * 16) >> 3) + (lg >> 1);
      *(bfx4*)(smX + b * 512 + ((chunk5 ^ (b & 7)) << 4) + ((lg & 1) << 3)) = p;
    }
  __syncthreads();   // B4

  // ---- ut*dt fragments
  const float dtv = dtp[0];
  bfx8 ufrag[4];
  #pragma unroll
  for (int nt = 0; nt < 4; ++nt) {
    const float* up = ut + (size_t)(b0 + nt * 16 + lr) * UU + (lg << 3);
    float4 u0 = *(const float4*)up;
    float4 u1 = *(const float4*)(up + 4);
    bfx8 v;
    v[0] = f2bf(u0.x * dtv); v[1] = f2bf(u0.y * dtv);
    v[2] = f2bf(u0.z * dtv); v[3] = f2bf(u0.w * dtv);
    v[4] = f2bf(u1.x * dtv); v[5] = f2bf(u1.y * dtv);
    v[6] = f2bf(u1.z * dtv); v[7] = f2bf(u1.w * dtv);
    ufrag[nt] = v;
  }

  // ---- GEMM3: binT[r][b] = rnnB @ [g, ut*dt]^T  (K=288, NKT=9)
  fx4 acc3[2][4];
  #pragma unroll
  for (int mt = 0; mt < 2; ++mt)
    #pragma unroll
    for (int nt = 0; nt < 4; ++nt)
      acc3[mt][nt] = (fx4){0.f, 0.f, 0.f, 0.f};
  {
    const u16* rpk = rnnb + (size_t)n * 73728;
    #pragma unroll
    for (int kk = 0; kk < 8; ++kk) {
      bfx8 gb[4];
      #pragma unroll
      for (int nt = 0; nt < 4; ++nt) {
        int b = nt * 16 + lr;
        gb[nt] = *(const bfx8*)(smX + b * 512 + ((((kk << 2) + lg) ^ (b & 7)) << 4));
      }
      #pragma unroll
      for (int mt = 0; mt < 2; ++mt) {
        bfx8 af = *(const bfx8*)(rpk + (((((w << 1) + mt) * 9) + kk) << 9) + (l << 3));
        #pragma unroll
        for (int nt = 0; nt < 4; ++nt)
          acc3[mt][nt] = MFMA(af, gb[nt], acc3[mt][nt]);
      }
    }
    #pragma unroll
    for (int mt = 0; mt < 2; ++mt) {
      bfx8 af = *(const bfx8*)(rpk + (((((w << 1) + mt) * 9) + 8) << 9) + (l << 3));
      #pragma unroll
      for (int nt = 0; nt < 4; ++nt)
        acc3[mt][nt] = MFMA(af, ufrag[nt], acc3[mt][nt]);
    }
  }
  // pack bin -> smX[32K:64K]
  #pragma unroll
  for (int mt = 0; mt < 2; ++mt)
    #pragma unroll
    for (int nt = 0; nt < 4; ++nt) {
      int b = nt * 16 + lr;
      bfx4 p;
      p[0] = f2bf(acc3[mt][nt][0]); p[1] = f2bf(acc3[mt][nt][1]);
      p[2] = f2bf(acc3[mt][nt][2]); p[3] = f2bf(acc3[mt][nt][3]);
      int chunk5 = ((r0 + mt * 16) >> 3) + (lg >> 1);
      *(bfx4*)(smX + 32768 + b * 512 + ((chunk5 ^ (b & 7)) << 4) + ((lg & 1) << 3)) = p;
    }
  __syncthreads();   // B5 (bin ready; GEMM3 reads of g done)

  // ---- GEMM4: zt1pT[d][b] = Wout_pk[n] @ bin^T  (M=256 d, N=64, K=256)
  fx4 acc4[2][4];
  #pragma unroll
  for (int mt = 0; mt < 2; ++mt)
    #pragma unroll
    for (int nt = 0; nt < 4; ++nt)
      acc4[mt][nt] = (fx4){0.f, 0.f, 0.f, 0.f};
  {
    const u16* opk = wotpk + (size_t)n * 65536;
    #pragma unroll
    for (int kk = 0; kk < 8; ++kk) {
      bfx8 bf[4];
      #pragma unroll
      for (int nt = 0; nt < 4; ++nt) {
        int b = nt * 16 + lr;
        bf[nt] = *(const bfx8*)(smX + 32768 + b * 512 + ((((kk << 2) + lg) ^ (b & 7)) << 4));
      }
      #pragma unroll
      for (int mt = 0; mt < 2; ++mt) {
        bfx8 af = *(const bfx8*)(opk + (((((w << 1) + mt) << 3) + kk) << 9) + (l << 3));
        #pragma unroll
        for (int nt = 0; nt < 4; ++nt)
          acc4[mt][nt] = MFMA(af, bf[nt], acc4[mt][nt]);
      }
    }
  }
  // pack zt1 partial bf16 -> smX[0:32K] (g region dead after B5)
  #pragma unroll
  for (int mt = 0; mt < 2; ++mt)
    #pragma unroll
    for (int nt = 0; nt < 4; ++nt) {
      int b = nt * 16 + lr;
      bfx4 p;
      p[0] = f2bf(acc4[mt][nt][0]); p[1] = f2bf(acc4[mt][nt][1]);
      p[2] = f2bf(acc4[mt][nt][2]); p[3] = f2bf(acc4[mt][nt][3]);
      int chunk5 = ((r0 + mt * 16) >> 3) + (lg >> 1);   // d chunks
      *(bfx4*)(smX + b * 512 + ((chunk5 ^ (b & 7)) << 4) + ((lg & 1) << 3)) = p;
    }
  __syncthreads();   // B6

  // ---- write zt1p plane n in PHYSICAL chunk order (linear copy)
  {
    int c = tid & 31;
    #pragma unroll
    for (int j = 0; j < 4; ++j) {
      int row = (tid >> 5) + j * 16;
      int4 v = *(const int4*)(smX + row * 512 + (c << 4));
      *(int4*)(zt1p + (size_t)n * 4194304 + (size_t)(b0 + row) * 256 + c * 8) = v;
    }
  }
}

// ---------------------------------------------------------------------------
// reduce_y: zt1[b][d] = sum_n zt1p[n][b][phys], unswizzle, write fp32;
// then yt1 = zt1 @ C^T + dt*(ut @ Dm^T) from a padded LDS tile.
// 256 blocks x 256 thr, 64 batch rows/block.
// ---------------------------------------------------------------------------
__global__ __launch_bounds__(256)
void skolr_reduce_y(const u16* __restrict__ zt1p, const float* __restrict__ ut,
                    const float* __restrict__ dtp, const float* __restrict__ Cm,
                    const float* __restrict__ Dm, float* __restrict__ outp)
{
  __shared__ float sZ[64][260];   // pad 260: rows shift 4 banks -> y reads conflict-free
  const int tid = threadIdx.x;
  const int b0 = blockIdx.x * 64;

  #pragma unroll
  for (int p = 0; p < 8; ++p) {
    int q = tid + (p << 8);        // 0..2047
    int row = q >> 5, c = q & 31;
    size_t off = (size_t)(b0 + row) * 256 + c * 8;
    float s0 = 0.f, s1 = 0.f, s2 = 0.f, s3 = 0.f, s4 = 0.f, s5 = 0.f, s6 = 0.f, s7 = 0.f;
    #pragma unroll
    for (int n = 0; n < 8; ++n) {
      bfx8 v = *(const bfx8*)(zt1p + (size_t)n * 4194304 + off);
      s0 += bf2f((u16)v[0]); s1 += bf2f((u16)v[1]);
      s2 += bf2f((u16)v[2]); s3 += bf2f((u16)v[3]);
      s4 += bf2f((u16)v[4]); s5 += bf2f((u16)v[5]);
      s6 += bf2f((u16)v[6]); s7 += bf2f((u16)v[7]);
    }
    int d0 = (c ^ (row & 7)) << 3;   // unswizzle physical -> logical d
    float* op = outp + (size_t)(b0 + row) * DD + d0;
    *(float4*)op       = (float4){s0, s1, s2, s3};
    *(float4*)(op + 4) = (float4){s4, s5, s6, s7};
    float* zp = &sZ[row][d0];
    *(float4*)zp       = (float4){s0, s1, s2, s3};
    *(float4*)(zp + 4) = (float4){s4, s5, s6, s7};
  }
  __syncthreads();

  const float dtv = dtp[0];
  for (int i = tid; i < 64 * NY; i += 256) {
    int b = i / NY;
    int y = i - b * NY;
    const float* cp = Cm + y * DD;
    float s = 0.f;
    #pragma unroll 8
    for (int dc = 0; dc < 64; ++dc) {
      float4 z = *(const float4*)&sZ[b][dc * 4];
      float4 c = *(const float4*)(cp + dc * 4);
      s += z.x * c.x + z.y * c.y + z.z * c.z + z.w * c.w;
    }
    const float* up = ut + (size_t)(b0 + b) * UU;
    const float* dp = Dm + y * UU;
    float s2 = 0.f;
    #pragma unroll
    for (int u = 0; u < UU; u += 4) {
      float4 uu = *(const float4*)(up + u);
      float4 dd = *(const float4*)(dp + u);
      s2 += uu.x * dd.x + uu.y * dd.y + uu.z * dd.z + uu.w * dd.w;
    }
    outp[(size_t)B_TOT * DD + (size_t)(b0 + b) * NY + y] = s + dtv * s2;
  }
}

// ---------------------------------------------------------------------------
extern "C" void kernel_launch(void* const* d_in, const int* in_sizes, int n_in,
                              void* d_out, int out_size, void* d_ws, size_t ws_size,
                              hipStream_t stream)
{
  (void)in_sizes; (void)n_in; (void)out_size; (void)ws_size;
  const float* zt    = (const float*)d_in[0];
  const float* dtp   = (const float*)d_in[1];
  const float* ut    = (const float*)d_in[2];
  const float* gates = (const float*)d_in[3];
  const float* W1    = (const float*)d_in[4];
  const float* b1    = (const float*)d_in[5];
  const float* lng   = (const float*)d_in[6];
  const float* lnb   = (const float*)d_in[7];
  const float* W2    = (const float*)d_in[8];
  const float* b2    = (const float*)d_in[9];
  // d_in[10]=lam_r, d_in[11]=lam_i unused (h0 = 0 => lambda drops out)
  const float* rnnB  = (const float*)d_in[12];
  const float* Wout  = (const float*)d_in[13];
  const float* Cm    = (const float*)d_in[14];
  const float* Dm    = (const float*)d_in[15];
  float* outp = (float*)d_out;
  char* ws = (char*)d_ws;

  u16* w1g  = (u16*)(ws + 0);           //  2,097,152 B
  u16* w2b  = (u16*)(ws + 2097152);     //  2,097,152 B
  u16* bb   = (u16*)(ws + 4194304);     //  1,179,648 B
  u16* wotb = (u16*)(ws + 5373952);     //  1,048,576 B (per-branch packed)
  u16* ztb  = (u16*)(ws + 6422528);     //  8,388,608 B
  u16* zt1p = (u16*)(ws + 14811136);    // 67,108,864 B (8 planes x 8 MB)

  skolr_prep<<<3616, 256, 0, stream>>>(W1, W2, rnnB, Wout, gates, zt,
                                       w1g, w2b, bb, wotb, ztb);
  skolr_fused<<<dim3(8, 256), 512, 0, stream>>>(ztb, dtp, ut, w1g, b1, lng, lnb,
                                                w2b, b2, bb, wotb, zt1p);
  skolr_reduce_y<<<256, 256, 0, stream>>>(zt1p, ut, dtp, Cm, Dm, outp);
}